// Round 22
// baseline (116.296 us; speedup 1.0000x reference)
//
#include <hip/hip_runtime.h>
#include <hip/hip_bf16.h>

typedef unsigned short u16;
typedef __attribute__((ext_vector_type(8))) __bf16 bf16x8;
typedef __attribute__((ext_vector_type(4))) float f32x4;
typedef __attribute__((ext_vector_type(2))) unsigned int u32x2;

#define S_LEN 2048
#define DMODEL 1024
#define NHEAD 16
#define HSZ 64

__device__ __forceinline__ u16 f2bf(float f) {
  union { __hip_bfloat16 b; u16 u; } c;
  c.b = __float2bfloat16(f);
  return c.u;
}

__device__ __forceinline__ float bf2f(u16 u) {
  union { unsigned int i; float f; } c;
  c.i = ((unsigned int)u) << 16;
  return c.f;
}

// raw v_exp_f32 (D = 2^S0)
__device__ __forceinline__ float fexp2(float x) {
#if __has_builtin(__builtin_amdgcn_exp2f)
  return __builtin_amdgcn_exp2f(x);
#else
  return exp2f(x);
#endif
}

// v_cvt_pk_bf16_f32: pack 2 f32 -> 2 bf16 (RNE)
__device__ __forceinline__ unsigned int cvtpk(float lo, float hi) {
  unsigned int r;
  asm("v_cvt_pk_bf16_f32 %0, %1, %2" : "=v"(r) : "v"(lo), "v"(hi));
  return r;
}

// ---- VALU butterfly reduce steps via permlane swaps (vs ds_bpermute shfl) ----
__device__ __forceinline__ float redmax16(float x) {
#if __has_builtin(__builtin_amdgcn_permlane16_swap)
  union { float f; unsigned u; } c; c.f = x;
  u32x2 r = __builtin_amdgcn_permlane16_swap(c.u, c.u, false, false);
  union { unsigned u; float f; } a, b; a.u = r.x; b.u = r.y;
  return fmaxf(a.f, b.f);
#else
  return fmaxf(x, __shfl_xor(x, 16));
#endif
}
__device__ __forceinline__ float redmax32(float x) {
#if __has_builtin(__builtin_amdgcn_permlane32_swap)
  union { float f; unsigned u; } c; c.f = x;
  u32x2 r = __builtin_amdgcn_permlane32_swap(c.u, c.u, false, false);
  union { unsigned u; float f; } a, b; a.u = r.x; b.u = r.y;
  return fmaxf(a.f, b.f);
#else
  return fmaxf(x, __shfl_xor(x, 32));
#endif
}
__device__ __forceinline__ float redadd16(float x) {
#if __has_builtin(__builtin_amdgcn_permlane16_swap)
  union { float f; unsigned u; } c; c.f = x;
  u32x2 r = __builtin_amdgcn_permlane16_swap(c.u, c.u, false, false);
  union { unsigned u; float f; } a, b; a.u = r.x; b.u = r.y;
  return a.f + b.f;
#else
  return x + __shfl_xor(x, 16);
#endif
}
__device__ __forceinline__ float redadd32(float x) {
#if __has_builtin(__builtin_amdgcn_permlane32_swap)
  union { float f; unsigned u; } c; c.f = x;
  u32x2 r = __builtin_amdgcn_permlane32_swap(c.u, c.u, false, false);
  union { unsigned u; float f; } a, b; a.u = r.x; b.u = r.y;
  return a.f + b.f;
#else
  return x + __shfl_xor(x, 32);
#endif
}

__device__ __forceinline__ void gload_lds16(const void* g, void* l) {
  __builtin_amdgcn_global_load_lds(
      (const __attribute__((address_space(1))) void*)g,
      (__attribute__((address_space(3))) void*)l, 16, 0, 0);
}

__device__ __forceinline__ f32x4 mfma16(bf16x8 a, bf16x8 b, f32x4 c) {
  return __builtin_amdgcn_mfma_f32_16x16x32_bf16(a, b, c, 0, 0, 0);
}

// ------- merged prep: blocks [0,4096) convert q -> bf16; [4096,5120) transpose W -------
__global__ __launch_bounds__(256) void prep_kernel(
    const float* __restrict__ qin, u16* __restrict__ Xb,
    const float* __restrict__ W0, const float* __restrict__ W1,
    const float* __restrict__ W2, const float* __restrict__ W3,
    u16* __restrict__ T0, u16* __restrict__ T1,
    u16* __restrict__ T2, u16* __restrict__ T3) {
  __shared__ float tile[64][65];
  int bid = blockIdx.x;
  int t = threadIdx.x;
  if (bid < 4096) {
    int i = (bid * 256 + t) * 4;
    float4 v = *(const float4*)(qin + i);
    ushort4 o;
    o.x = f2bf(v.x); o.y = f2bf(v.y); o.z = f2bf(v.z); o.w = f2bf(v.w);
    *(ushort4*)(Xb + i) = o;
    return;
  }
  int id = bid - 4096;
  int z = id >> 8;
  int r = id & 255;
  int k0 = (r >> 4) * 64, n0 = (r & 15) * 64;
  const float* W = (z == 0) ? W0 : ((z == 1) ? W1 : ((z == 2) ? W2 : W3));
  u16* T = (z == 0) ? T0 : ((z == 1) ? T1 : ((z == 2) ? T2 : T3));
#pragma unroll
  for (int j = 0; j < 4; ++j) {
    int idx = j * 256 + t;
    int row = idx >> 4, c4 = idx & 15;
    float4 v = *(const float4*)(W + (size_t)(k0 + row) * DMODEL + n0 + c4 * 4);
    tile[row][c4 * 4 + 0] = v.x; tile[row][c4 * 4 + 1] = v.y;
    tile[row][c4 * 4 + 2] = v.z; tile[row][c4 * 4 + 3] = v.w;
  }
  __syncthreads();
#pragma unroll
  for (int j = 0; j < 4; ++j) {
    int idx = j * 256 + t;
    int orow = idx >> 4, c4 = idx & 15;
    ushort4 o;
    o.x = f2bf(tile[c4 * 4 + 0][orow]);
    o.y = f2bf(tile[c4 * 4 + 1][orow]);
    o.z = f2bf(tile[c4 * 4 + 2][orow]);
    o.w = f2bf(tile[c4 * 4 + 3][orow]);
    *(ushort4*)(T + (size_t)(n0 + orow) * DMODEL + k0 + c4 * 4) = o;
  }
}

// ------------- GEMM core, templated on m-frags/wave (WM*32 = tile rows) -------------
template <int WM>
__device__ __forceinline__ void gemm_core(const u16* __restrict__ A,
                                          const u16* __restrict__ Bt,
                                          u16* ldsbuf, f32x4 (&acc)[WM][4],
                                          int m0, int n0) {
  const int t = threadIdx.x;
  const int wave = t >> 6, lane = t & 63;
  const int l15 = lane & 15, l4 = lane >> 4;
  const int wr = wave >> 1, wc = wave & 1;
  u16* Asm = ldsbuf;                 // [WM*32][32]
  u16* Bsm = ldsbuf + WM * 1024;     // [128][32]
  for (int kt = 0; kt < DMODEL / 32; ++kt) {
    int kb = kt * 32;
#pragma unroll
    for (int j = 0; j < WM / 2; ++j) {
      int ci = j * 256 + t;
      int row = ci >> 2, kc = ci & 3;
      gload_lds16(A + (size_t)(m0 + row) * DMODEL + kb + kc * 8,
                  Asm + (j * 256 + wave * 64) * 8);
    }
#pragma unroll
    for (int j = 0; j < 2; ++j) {
      int ci = j * 256 + t;
      int row = ci >> 2, kc = ci & 3;
      gload_lds16(Bt + (size_t)(n0 + row) * DMODEL + kb + kc * 8,
                  Bsm + (j * 256 + wave * 64) * 8);
    }
    __syncthreads();
    bf16x8 af[WM], bfr[4];
#pragma unroll
    for (int m = 0; m < WM; ++m)
      af[m] = *(const bf16x8*)(Asm + ((wr * (WM * 16) + m * 16 + l15) * 32 + l4 * 8));
#pragma unroll
    for (int n = 0; n < 4; ++n)
      bfr[n] = *(const bf16x8*)(Bsm + ((wc * 64 + n * 16 + l15) * 32 + l4 * 8));
#pragma unroll
    for (int m = 0; m < WM; ++m)
#pragma unroll
      for (int n = 0; n < 4; ++n)
        acc[m][n] = mfma16(af[m], bfr[n], acc[m][n]);
    __syncthreads();
  }
}

// ------------- QKV projection; Q pre-scaled by 0.125*log2(e); XCD-swizzled grid -------------
__global__ __launch_bounds__(256) void gemm_qkv_kernel(
    const u16* __restrict__ A, const u16* __restrict__ B0, const u16* __restrict__ B1,
    const u16* __restrict__ B2, const float* __restrict__ bias0,
    const float* __restrict__ bias1, const float* __restrict__ bias2,
    u16* __restrict__ d0, u16* __restrict__ d1, u16* __restrict__ d2) {
  __shared__ __align__(16) u16 lds[8192];
  const int id = blockIdx.x;
  const int w = (id & 7) * 96 + (id >> 3);  // bijective XCD chunking
  const int z = w >> 8;
  const int rem = w & 255;
  const int by = rem >> 3, bx = rem & 7;
  const u16* Bt = (z == 0) ? B0 : ((z == 1) ? B1 : B2);
  const float* bias = (z == 0) ? bias0 : ((z == 1) ? bias1 : bias2);
  u16* dst = (z == 0) ? d0 : ((z == 1) ? d1 : d2);
  const float sc = (z == 0) ? 0.18033688011112042f : 1.0f;  // 0.125*log2e
  int m0 = by * 128, n0 = bx * 128;
  f32x4 acc[4][4] = {};
  gemm_core<4>(A, Bt, lds, acc, m0, n0);
  const int t = threadIdx.x;
  const int wave = t >> 6, lane = t & 63, l15 = lane & 15, l4 = lane >> 4;
  const int wr = wave >> 1, wc = wave & 1;
#pragma unroll
  for (int n = 0; n < 4; ++n) {
    int colg = n0 + wc * 64 + n * 16 + l15;
    float bn = bias[colg];
    int h = colg >> 6, hs = colg & 63;
#pragma unroll
    for (int m = 0; m < 4; ++m) {
#pragma unroll
      for (int i = 0; i < 4; ++i) {
        int rowg = m0 + wr * 64 + m * 16 + 4 * l4 + i;
        int b = rowg >> 11, s = rowg & 2047;
        dst[(size_t)(b * NHEAD + h) * S_LEN * HSZ + (size_t)s * HSZ + hs] =
            f2bf((acc[m][n][i] + bn) * sc);
      }
    }
  }
}

// ------------- output projection: 64x128 tile (WM=2), fp32 out -------------
__global__ __launch_bounds__(256) void gemm_out_kernel(const u16* __restrict__ A,
                                                       const u16* __restrict__ Bt,
                                                       const float* __restrict__ bias,
                                                       float* __restrict__ out) {
  __shared__ __align__(16) u16 lds[6144];
  int m0 = blockIdx.y * 64, n0 = blockIdx.x * 128;
  f32x4 acc[2][4] = {};
  gemm_core<2>(A, Bt, lds, acc, m0, n0);
  const int t = threadIdx.x;
  const int wave = t >> 6, lane = t & 63, l15 = lane & 15, l4 = lane >> 4;
  const int wr = wave >> 1, wc = wave & 1;
#pragma unroll
  for (int n = 0; n < 4; ++n) {
    int colg = n0 + wc * 64 + n * 16 + l15;
    float bn = bias[colg];
#pragma unroll
    for (int m = 0; m < 2; ++m) {
#pragma unroll
      for (int i = 0; i < 4; ++i) {
        int rowg = m0 + wr * 32 + m * 16 + 4 * l4 + i;
        out[(size_t)rowg * DMODEL + colg] = acc[m][n][i] + bn;
      }
    }
  }
}

// ------------- flash attention (causal), LDS-shared K/V, transpose-on-stage -------------
// (R21 champion) + V is read RAW from Vh [bh][S][64] and transposed during the
// LDS stage-write (16 x ds_write_b16 w/ immediate offsets) -> the transpose_v
// kernel (16MB round-trip + launch) is deleted. Vsm content & all compute
// byte-identical to R21.
__global__ __launch_bounds__(256, 2) void attn_kernel(const u16* __restrict__ Qh,
                                                      const u16* __restrict__ Kh,
                                                      const u16* __restrict__ Vh,
                                                      u16* __restrict__ Ob) {
  __shared__ __align__(16) u16 Ksm[2][64][72];   // [buf][kv][hs]
  __shared__ __align__(16) u16 Vsm[2][64][72];   // [buf][hs][kv]
  __shared__ __align__(16) u16 Pl[4][16][72];    // per-wave P
  const int tixd = threadIdx.x;
  const int wave = tixd >> 6, lane = tixd & 63;
  const int l15 = lane & 15, l4 = lane >> 4;
  const int id = blockIdx.x;
  const int bh = (id & 7) * 4 + ((id >> 3) & 3);  // XCD-local heads
  const int pk = id >> 5;                         // pair index 0..15
  const u16* Qb = Qh + (size_t)bh * S_LEN * HSZ;
  const u16* Kb = Kh + (size_t)bh * S_LEN * HSZ;
  const u16* Vb = Vh + (size_t)bh * S_LEN * HSZ;  // raw [s][hs]
  const int shbase = l4 * 20;
  u16 (*P)[72] = Pl[wave];
  const int b = bh >> 4, h = bh & 15;
  // staging: 256 threads -> row sr in [0,64), col base scb in {0,16,32,48}
  const int sr = tixd >> 2;
  const int scb = (tixd & 3) * 16;

#pragma unroll 1
  for (int ph = 0; ph < 2; ++ph) {
    const int pp = ph ? (31 - pk) : pk;     // q-tile of 64 rows
    const int q0 = pp * 64 + wave * 16;     // this wave's 16 rows
    const int nt = pp + 1;                  // staged kv tiles of 64

    bf16x8 qf[2];
#pragma unroll
    for (int kc = 0; kc < 2; ++kc)
      qf[kc] = *(const bf16x8*)(Qb + (size_t)(q0 + l15) * HSZ + kc * 32 + l4 * 8);

    f32x4 oacc[4] = {};
    float mrun = -1e30f;
    float lrun = 0.f;

    // prologue: tile 0 -> regs; barrier so prior phase's readers are done
    uint4 ka0 = *(const uint4*)(Kb + (size_t)sr * HSZ + scb);
    uint4 ka1 = *(const uint4*)(Kb + (size_t)sr * HSZ + scb + 8);
    uint4 va0 = *(const uint4*)(Vb + (size_t)sr * HSZ + scb);
    uint4 va1 = *(const uint4*)(Vb + (size_t)sr * HSZ + scb + 8);
    __syncthreads();
    *(uint4*)&Ksm[0][sr][scb]     = ka0;
    *(uint4*)&Ksm[0][sr][scb + 8] = ka1;
#pragma unroll
    for (int j = 0; j < 8; ++j) {
      Vsm[0][scb + j][sr]     = ((const u16*)&va0)[j];
      Vsm[0][scb + 8 + j][sr] = ((const u16*)&va1)[j];
    }

#pragma unroll 1
    for (int t = 0; t < nt; ++t) {
      const int cur = t & 1;
      if (t + 1 < nt) {  // issue next-tile loads; land during compute below
        const int kvn = (t + 1) * 64;
        ka0 = *(const uint4*)(Kb + (size_t)(kvn + sr) * HSZ + scb);
        ka1 = *(const uint4*)(Kb + (size_t)(kvn + sr) * HSZ + scb + 8);
        va0 = *(const uint4*)(Vb + (size_t)(kvn + sr) * HSZ + scb);
        va1 = *(const uint4*)(Vb + (size_t)(kvn + sr) * HSZ + scb + 8);
      }
      __syncthreads();  // tile t's writes visible; readers of buf[cur] (t-2) done
      const int kv0 = t * 64;

      bf16x8 kf[4][2];
#pragma unroll
      for (int n = 0; n < 4; ++n)
#pragma unroll
        for (int kc = 0; kc < 2; ++kc)
          kf[n][kc] = *(const bf16x8*)&Ksm[cur][n * 16 + l15][kc * 32 + l4 * 8];

      f32x4 sacc[4] = {};
#pragma unroll
      for (int n = 0; n < 4; ++n) {
        sacc[n] = mfma16(kf[n][0], qf[0], sacc[n]);
        sacc[n] = mfma16(kf[n][1], qf[1], sacc[n]);
      }

      bf16x8 vf[2][4];
#pragma unroll
      for (int kb = 0; kb < 2; ++kb)
#pragma unroll
        for (int n = 0; n < 4; ++n)
          vf[kb][n] = *(const bf16x8*)&Vsm[cur][n * 16 + l15][kb * 32 + l4 * 8];

      if (kv0 + 63 > q0) {
#pragma unroll
        for (int n = 0; n < 4; ++n)
#pragma unroll
          for (int i = 0; i < 4; ++i)
            if (kv0 + n * 16 + 4 * l4 + i > q0 + l15) sacc[n][i] = -1e30f;
      }

      {
        float a0 = fmaxf(fmaxf(sacc[0][0], sacc[0][1]),
                         fmaxf(sacc[0][2], sacc[0][3]));
        float a1 = fmaxf(fmaxf(sacc[1][0], sacc[1][1]),
                         fmaxf(sacc[1][2], sacc[1][3]));
        float a2 = fmaxf(fmaxf(sacc[2][0], sacc[2][1]),
                         fmaxf(sacc[2][2], sacc[2][3]));
        float a3 = fmaxf(fmaxf(sacc[3][0], sacc[3][1]),
                         fmaxf(sacc[3][2], sacc[3][3]));
        float tm = fmaxf(fmaxf(a0, a1), fmaxf(a2, a3));
        tm = redmax16(tm);
        tm = redmax32(tm);
        float mr = mrun;
        if (__all(tm <= mr + 8.0f)) {
          // defer-max: no rescale; P bounded by 2^8
          float rs = 0.f;
#pragma unroll
          for (int n = 0; n < 4; ++n)
#pragma unroll
            for (int i = 0; i < 4; ++i) {
              float pv = fexp2(sacc[n][i] - mr);
              sacc[n][i] = pv;
              rs += pv;
            }
          rs = redadd16(rs);
          rs = redadd32(rs);
          lrun += rs;
        } else {
          float mnew = fmaxf(mr, tm);
          float corr = fexp2(mr - mnew);
          mrun = mnew;
          float rs = 0.f;
#pragma unroll
          for (int n = 0; n < 4; ++n)
#pragma unroll
            for (int i = 0; i < 4; ++i) {
              float pv = fexp2(sacc[n][i] - mnew);
              sacc[n][i] = pv;
              rs += pv;
            }
          rs = redadd16(rs);
          rs = redadd32(rs);
          lrun = lrun * corr + rs;
          float cc0 = __shfl(corr, shbase + 0);
          float cc1 = __shfl(corr, shbase + 1);
          float cc2 = __shfl(corr, shbase + 2);
          float cc3 = __shfl(corr, shbase + 3);
#pragma unroll
          for (int n = 0; n < 4; ++n) {
            oacc[n][0] *= cc0; oacc[n][1] *= cc1;
            oacc[n][2] *= cc2; oacc[n][3] *= cc3;
          }
        }
#pragma unroll
        for (int n = 0; n < 4; ++n) {
          uint2 pkk;
          pkk.x = cvtpk(sacc[n][0], sacc[n][1]);
          pkk.y = cvtpk(sacc[n][2], sacc[n][3]);
          *(uint2*)&P[l15][n * 16 + 4 * l4] = pkk;
        }
      }

#pragma unroll
      for (int kb = 0; kb < 2; ++kb) {
        bf16x8 pf = *(const bf16x8*)&P[l15][kb * 32 + l4 * 8];
#pragma unroll
        for (int n = 0; n < 4; ++n)
          oacc[n] = mfma16(pf, vf[kb][n], oacc[n]);
      }

      if (t + 1 < nt) {  // stage tile t+1 into the other buffer (off critical path)
        *(uint4*)&Ksm[cur ^ 1][sr][scb]     = ka0;
        *(uint4*)&Ksm[cur ^ 1][sr][scb + 8] = ka1;
#pragma unroll
        for (int j = 0; j < 8; ++j) {
          Vsm[cur ^ 1][scb + j][sr]     = ((const u16*)&va0)[j];
          Vsm[cur ^ 1][scb + 8 + j][sr] = ((const u16*)&va1)[j];
        }
      }
    }

    // finalize this wave's 16 rows directly
    {
      float invm = 1.0f / lrun;
#pragma unroll
      for (int i = 0; i < 4; ++i) {
        float iv = __shfl(invm, shbase + i);
        int srow = q0 + 4 * l4 + i;
#pragma unroll
        for (int n = 0; n < 4; ++n) {
          int d = h * HSZ + n * 16 + l15;
          Ob[((size_t)b * S_LEN + srow) * DMODEL + d] = f2bf(oacc[n][i] * iv);
        }
      }
    }
  }
}

extern "C" void kernel_launch(void* const* d_in, const int* in_sizes, int n_in,
                              void* d_out, int out_size, void* d_ws, size_t ws_size,
                              hipStream_t stream) {
  const float* q  = (const float*)d_in[0];
  const float* Wq = (const float*)d_in[1];
  const float* bq = (const float*)d_in[2];
  const float* Wk = (const float*)d_in[3];
  const float* bk = (const float*)d_in[4];
  const float* Wv = (const float*)d_in[5];
  const float* bv = (const float*)d_in[6];
  const float* Wo = (const float*)d_in[7];
  const float* bo = (const float*)d_in[8];

  char* ws = (char*)d_ws;
  const size_t MB = 1024 * 1024;
  u16* Xb  = (u16*)(ws + 0);        // 8 MB  [4096][1024] bf16
  u16* WqT = (u16*)(ws + 8 * MB);   // 2 MB  [N][K] bf16
  u16* WkT = (u16*)(ws + 10 * MB);
  u16* WvT = (u16*)(ws + 12 * MB);
  u16* WoT = (u16*)(ws + 14 * MB);
  u16* Qh  = (u16*)(ws + 16 * MB);  // 8 MB  [bh][S][64]
  u16* Kh  = (u16*)(ws + 24 * MB);
  u16* Vh  = (u16*)(ws + 32 * MB);  // 8 MB  [bh][S][64] (raw; attn transposes on stage)
  u16* Ob  = (u16*)(ws + 48 * MB);  // 8 MB  [B,S,D]

  prep_kernel<<<5120, 256, 0, stream>>>(q, Xb, Wq, Wk, Wv, Wo,
                                        WqT, WkT, WvT, WoT);
  gemm_qkv_kernel<<<768, 256, 0, stream>>>(Xb, WqT, WkT, WvT,
                                           bq, bk, bv, Qh, Kh, Vh);
  attn_kernel<<<512, 256, 0, stream>>>(Qh, Kh, Vh, Ob);
  gemm_out_kernel<<<dim3(8, 64), 256, 0, stream>>>(Ob, WoT, bo, (float*)d_out);
}

// Round 23
// 108.214 us; speedup vs baseline: 1.0747x; 1.0747x over previous
//
#include <hip/hip_runtime.h>
#include <hip/hip_bf16.h>

typedef unsigned short u16;
typedef __attribute__((ext_vector_type(8))) __bf16 bf16x8;
typedef __attribute__((ext_vector_type(4))) float f32x4;
typedef __attribute__((ext_vector_type(2))) unsigned int u32x2;

#define S_LEN 2048
#define DMODEL 1024
#define NHEAD 16
#define HSZ 64

__device__ __forceinline__ u16 f2bf(float f) {
  union { __hip_bfloat16 b; u16 u; } c;
  c.b = __float2bfloat16(f);
  return c.u;
}

__device__ __forceinline__ float bf2f(u16 u) {
  union { unsigned int i; float f; } c;
  c.i = ((unsigned int)u) << 16;
  return c.f;
}

// raw v_exp_f32 (D = 2^S0)
__device__ __forceinline__ float fexp2(float x) {
#if __has_builtin(__builtin_amdgcn_exp2f)
  return __builtin_amdgcn_exp2f(x);
#else
  return exp2f(x);
#endif
}

// v_cvt_pk_bf16_f32: pack 2 f32 -> 2 bf16 (RNE)
__device__ __forceinline__ unsigned int cvtpk(float lo, float hi) {
  unsigned int r;
  asm("v_cvt_pk_bf16_f32 %0, %1, %2" : "=v"(r) : "v"(lo), "v"(hi));
  return r;
}

// ---- VALU butterfly reduce steps via permlane swaps (vs ds_bpermute shfl) ----
__device__ __forceinline__ float redmax16(float x) {
#if __has_builtin(__builtin_amdgcn_permlane16_swap)
  union { float f; unsigned u; } c; c.f = x;
  u32x2 r = __builtin_amdgcn_permlane16_swap(c.u, c.u, false, false);
  union { unsigned u; float f; } a, b; a.u = r.x; b.u = r.y;
  return fmaxf(a.f, b.f);
#else
  return fmaxf(x, __shfl_xor(x, 16));
#endif
}
__device__ __forceinline__ float redmax32(float x) {
#if __has_builtin(__builtin_amdgcn_permlane32_swap)
  union { float f; unsigned u; } c; c.f = x;
  u32x2 r = __builtin_amdgcn_permlane32_swap(c.u, c.u, false, false);
  union { unsigned u; float f; } a, b; a.u = r.x; b.u = r.y;
  return fmaxf(a.f, b.f);
#else
  return fmaxf(x, __shfl_xor(x, 32));
#endif
}
__device__ __forceinline__ float redadd16(float x) {
#if __has_builtin(__builtin_amdgcn_permlane16_swap)
  union { float f; unsigned u; } c; c.f = x;
  u32x2 r = __builtin_amdgcn_permlane16_swap(c.u, c.u, false, false);
  union { unsigned u; float f; } a, b; a.u = r.x; b.u = r.y;
  return a.f + b.f;
#else
  return x + __shfl_xor(x, 16);
#endif
}
__device__ __forceinline__ float redadd32(float x) {
#if __has_builtin(__builtin_amdgcn_permlane32_swap)
  union { float f; unsigned u; } c; c.f = x;
  u32x2 r = __builtin_amdgcn_permlane32_swap(c.u, c.u, false, false);
  union { unsigned u; float f; } a, b; a.u = r.x; b.u = r.y;
  return a.f + b.f;
#else
  return x + __shfl_xor(x, 32);
#endif
}

__device__ __forceinline__ void gload_lds16(const void* g, void* l) {
  __builtin_amdgcn_global_load_lds(
      (const __attribute__((address_space(1))) void*)g,
      (__attribute__((address_space(3))) void*)l, 16, 0, 0);
}

__device__ __forceinline__ f32x4 mfma16(bf16x8 a, bf16x8 b, f32x4 c) {
  return __builtin_amdgcn_mfma_f32_16x16x32_bf16(a, b, c, 0, 0, 0);
}

// ------- merged prep: blocks [0,4096) convert q -> bf16; [4096,5120) transpose W -------
__global__ __launch_bounds__(256) void prep_kernel(
    const float* __restrict__ qin, u16* __restrict__ Xb,
    const float* __restrict__ W0, const float* __restrict__ W1,
    const float* __restrict__ W2, const float* __restrict__ W3,
    u16* __restrict__ T0, u16* __restrict__ T1,
    u16* __restrict__ T2, u16* __restrict__ T3) {
  __shared__ float tile[64][65];
  int bid = blockIdx.x;
  int t = threadIdx.x;
  if (bid < 4096) {
    int i = (bid * 256 + t) * 4;
    float4 v = *(const float4*)(qin + i);
    ushort4 o;
    o.x = f2bf(v.x); o.y = f2bf(v.y); o.z = f2bf(v.z); o.w = f2bf(v.w);
    *(ushort4*)(Xb + i) = o;
    return;
  }
  int id = bid - 4096;
  int z = id >> 8;
  int r = id & 255;
  int k0 = (r >> 4) * 64, n0 = (r & 15) * 64;
  const float* W = (z == 0) ? W0 : ((z == 1) ? W1 : ((z == 2) ? W2 : W3));
  u16* T = (z == 0) ? T0 : ((z == 1) ? T1 : ((z == 2) ? T2 : T3));
#pragma unroll
  for (int j = 0; j < 4; ++j) {
    int idx = j * 256 + t;
    int row = idx >> 4, c4 = idx & 15;
    float4 v = *(const float4*)(W + (size_t)(k0 + row) * DMODEL + n0 + c4 * 4);
    tile[row][c4 * 4 + 0] = v.x; tile[row][c4 * 4 + 1] = v.y;
    tile[row][c4 * 4 + 2] = v.z; tile[row][c4 * 4 + 3] = v.w;
  }
  __syncthreads();
#pragma unroll
  for (int j = 0; j < 4; ++j) {
    int idx = j * 256 + t;
    int orow = idx >> 4, c4 = idx & 15;
    ushort4 o;
    o.x = f2bf(tile[c4 * 4 + 0][orow]);
    o.y = f2bf(tile[c4 * 4 + 1][orow]);
    o.z = f2bf(tile[c4 * 4 + 2][orow]);
    o.w = f2bf(tile[c4 * 4 + 3][orow]);
    *(ushort4*)(T + (size_t)(n0 + orow) * DMODEL + k0 + c4 * 4) = o;
  }
}

// ------------- Vh [bh][S][64] -> Vt [bh][64][S] bf16 -------------
__global__ __launch_bounds__(256) void transpose_v_kernel(const u16* __restrict__ Vh,
                                                          u16* __restrict__ Vt) {
  int bh = blockIdx.y;
  int s0 = blockIdx.x * 64;
  __shared__ __align__(16) u16 tile[64][72];
  int t = threadIdx.x;
#pragma unroll
  for (int j = 0; j < 4; ++j) {
    int idx = j * 256 + t;
    int row = idx >> 4, c4 = idx & 15;
    *(ushort4*)&tile[row][c4 * 4] =
        *(const ushort4*)(Vh + ((size_t)bh * S_LEN + s0 + row) * HSZ + c4 * 4);
  }
  __syncthreads();
#pragma unroll
  for (int j = 0; j < 4; ++j) {
    int idx = j * 256 + t;
    int orow = idx >> 4, c4 = idx & 15;
    ushort4 o;
    o.x = tile[c4 * 4 + 0][orow];
    o.y = tile[c4 * 4 + 1][orow];
    o.z = tile[c4 * 4 + 2][orow];
    o.w = tile[c4 * 4 + 3][orow];
    *(ushort4*)(Vt + ((size_t)bh * HSZ + orow) * S_LEN + s0 + c4 * 4) = o;
  }
}

// ------------- GEMM core, templated on m-frags/wave (WM*32 = tile rows) -------------
template <int WM>
__device__ __forceinline__ void gemm_core(const u16* __restrict__ A,
                                          const u16* __restrict__ Bt,
                                          u16* ldsbuf, f32x4 (&acc)[WM][4],
                                          int m0, int n0) {
  const int t = threadIdx.x;
  const int wave = t >> 6, lane = t & 63;
  const int l15 = lane & 15, l4 = lane >> 4;
  const int wr = wave >> 1, wc = wave & 1;
  u16* Asm = ldsbuf;                 // [WM*32][32]
  u16* Bsm = ldsbuf + WM * 1024;     // [128][32]
  for (int kt = 0; kt < DMODEL / 32; ++kt) {
    int kb = kt * 32;
#pragma unroll
    for (int j = 0; j < WM / 2; ++j) {
      int ci = j * 256 + t;
      int row = ci >> 2, kc = ci & 3;
      gload_lds16(A + (size_t)(m0 + row) * DMODEL + kb + kc * 8,
                  Asm + (j * 256 + wave * 64) * 8);
    }
#pragma unroll
    for (int j = 0; j < 2; ++j) {
      int ci = j * 256 + t;
      int row = ci >> 2, kc = ci & 3;
      gload_lds16(Bt + (size_t)(n0 + row) * DMODEL + kb + kc * 8,
                  Bsm + (j * 256 + wave * 64) * 8);
    }
    __syncthreads();
    bf16x8 af[WM], bfr[4];
#pragma unroll
    for (int m = 0; m < WM; ++m)
      af[m] = *(const bf16x8*)(Asm + ((wr * (WM * 16) + m * 16 + l15) * 32 + l4 * 8));
#pragma unroll
    for (int n = 0; n < 4; ++n)
      bfr[n] = *(const bf16x8*)(Bsm + ((wc * 64 + n * 16 + l15) * 32 + l4 * 8));
#pragma unroll
    for (int m = 0; m < WM; ++m)
#pragma unroll
      for (int n = 0; n < 4; ++n)
        acc[m][n] = mfma16(af[m], bfr[n], acc[m][n]);
    __syncthreads();
  }
}

// ------------- QKV projection; Q pre-scaled by 0.125*log2(e); XCD-swizzled grid -------------
__global__ __launch_bounds__(256) void gemm_qkv_kernel(
    const u16* __restrict__ A, const u16* __restrict__ B0, const u16* __restrict__ B1,
    const u16* __restrict__ B2, const float* __restrict__ bias0,
    const float* __restrict__ bias1, const float* __restrict__ bias2,
    u16* __restrict__ d0, u16* __restrict__ d1, u16* __restrict__ d2) {
  __shared__ __align__(16) u16 lds[8192];
  const int id = blockIdx.x;
  const int w = (id & 7) * 96 + (id >> 3);  // bijective XCD chunking
  const int z = w >> 8;
  const int rem = w & 255;
  const int by = rem >> 3, bx = rem & 7;
  const u16* Bt = (z == 0) ? B0 : ((z == 1) ? B1 : B2);
  const float* bias = (z == 0) ? bias0 : ((z == 1) ? bias1 : bias2);
  u16* dst = (z == 0) ? d0 : ((z == 1) ? d1 : d2);
  const float sc = (z == 0) ? 0.18033688011112042f : 1.0f;  // 0.125*log2e
  int m0 = by * 128, n0 = bx * 128;
  f32x4 acc[4][4] = {};
  gemm_core<4>(A, Bt, lds, acc, m0, n0);
  const int t = threadIdx.x;
  const int wave = t >> 6, lane = t & 63, l15 = lane & 15, l4 = lane >> 4;
  const int wr = wave >> 1, wc = wave & 1;
#pragma unroll
  for (int n = 0; n < 4; ++n) {
    int colg = n0 + wc * 64 + n * 16 + l15;
    float bn = bias[colg];
    int h = colg >> 6, hs = colg & 63;
#pragma unroll
    for (int m = 0; m < 4; ++m) {
#pragma unroll
      for (int i = 0; i < 4; ++i) {
        int rowg = m0 + wr * 64 + m * 16 + 4 * l4 + i;
        int b = rowg >> 11, s = rowg & 2047;
        dst[(size_t)(b * NHEAD + h) * S_LEN * HSZ + (size_t)s * HSZ + hs] =
            f2bf((acc[m][n][i] + bn) * sc);
      }
    }
  }
}

// ------------- output projection: 64x128 tile (WM=2), fp32 out, XCD-swizzled -------------
__global__ __launch_bounds__(256) void gemm_out_kernel(const u16* __restrict__ A,
                                                       const u16* __restrict__ Bt,
                                                       const float* __restrict__ bias,
                                                       float* __restrict__ out) {
  __shared__ __align__(16) u16 lds[6144];
  const int id = blockIdx.x;
  const int w = (id & 7) * 64 + (id >> 3);  // bijective: 512 = 8 * 64
  int m0 = (w >> 3) * 64, n0 = (w & 7) * 128;
  f32x4 acc[2][4] = {};
  gemm_core<2>(A, Bt, lds, acc, m0, n0);
  const int t = threadIdx.x;
  const int wave = t >> 6, lane = t & 63, l15 = lane & 15, l4 = lane >> 4;
  const int wr = wave >> 1, wc = wave & 1;
#pragma unroll
  for (int n = 0; n < 4; ++n) {
    int colg = n0 + wc * 64 + n * 16 + l15;
    float bn = bias[colg];
#pragma unroll
    for (int m = 0; m < 2; ++m) {
#pragma unroll
      for (int i = 0; i < 4; ++i) {
        int rowg = m0 + wr * 32 + m * 16 + 4 * l4 + i;
        out[(size_t)rowg * DMODEL + colg] = acc[m][n][i] + bn;
      }
    }
  }
}

// ------------- flash attention (causal), LDS-shared K/V, 2 blocks/CU, defer-max -------------
// (R21 champion, restored verbatim) 64-row blocks, 4 waves x 16 rows, grid 512
// = 2 blocks/CU, double-buffered K/V staging (b128 writes), one barrier/trip,
// pairing {p,31-p} -> 33 uniform trips, defer-max THR=8, permlane reduces.
__global__ __launch_bounds__(256, 2) void attn_kernel(const u16* __restrict__ Qh,
                                                      const u16* __restrict__ Kh,
                                                      const u16* __restrict__ Vt,
                                                      u16* __restrict__ Ob) {
  __shared__ __align__(16) u16 Ksm[2][64][72];   // [buf][kv][hs]
  __shared__ __align__(16) u16 Vsm[2][64][72];   // [buf][hs][kv]
  __shared__ __align__(16) u16 Pl[4][16][72];    // per-wave P
  const int tixd = threadIdx.x;
  const int wave = tixd >> 6, lane = tixd & 63;
  const int l15 = lane & 15, l4 = lane >> 4;
  const int id = blockIdx.x;
  const int bh = (id & 7) * 4 + ((id >> 3) & 3);  // XCD-local heads
  const int pk = id >> 5;                         // pair index 0..15
  const u16* Qb = Qh + (size_t)bh * S_LEN * HSZ;
  const u16* Kb = Kh + (size_t)bh * S_LEN * HSZ;
  const u16* Vb = Vt + (size_t)bh * HSZ * S_LEN;
  const int shbase = l4 * 20;
  u16 (*P)[72] = Pl[wave];
  const int b = bh >> 4, h = bh & 15;
  // staging: 256 threads -> row sr in [0,64), col base scb in {0,16,32,48}
  const int sr = tixd >> 2;
  const int scb = (tixd & 3) * 16;

#pragma unroll 1
  for (int ph = 0; ph < 2; ++ph) {
    const int pp = ph ? (31 - pk) : pk;     // q-tile of 64 rows
    const int q0 = pp * 64 + wave * 16;     // this wave's 16 rows
    const int nt = pp + 1;                  // staged kv tiles of 64

    bf16x8 qf[2];
#pragma unroll
    for (int kc = 0; kc < 2; ++kc)
      qf[kc] = *(const bf16x8*)(Qb + (size_t)(q0 + l15) * HSZ + kc * 32 + l4 * 8);

    f32x4 oacc[4] = {};
    float mrun = -1e30f;
    float lrun = 0.f;

    // prologue: tile 0 -> regs; barrier so prior phase's readers are done
    uint4 ka0 = *(const uint4*)(Kb + (size_t)sr * HSZ + scb);
    uint4 ka1 = *(const uint4*)(Kb + (size_t)sr * HSZ + scb + 8);
    uint4 va0 = *(const uint4*)(Vb + (size_t)sr * S_LEN + scb);
    uint4 va1 = *(const uint4*)(Vb + (size_t)sr * S_LEN + scb + 8);
    __syncthreads();
    *(uint4*)&Ksm[0][sr][scb]     = ka0;
    *(uint4*)&Ksm[0][sr][scb + 8] = ka1;
    *(uint4*)&Vsm[0][sr][scb]     = va0;
    *(uint4*)&Vsm[0][sr][scb + 8] = va1;

#pragma unroll 1
    for (int t = 0; t < nt; ++t) {
      const int cur = t & 1;
      if (t + 1 < nt) {  // issue next-tile loads; land during compute below
        const int kvn = (t + 1) * 64;
        ka0 = *(const uint4*)(Kb + (size_t)(kvn + sr) * HSZ + scb);
        ka1 = *(const uint4*)(Kb + (size_t)(kvn + sr) * HSZ + scb + 8);
        va0 = *(const uint4*)(Vb + (size_t)sr * S_LEN + kvn + scb);
        va1 = *(const uint4*)(Vb + (size_t)sr * S_LEN + kvn + scb + 8);
      }
      __syncthreads();  // tile t's writes visible; readers of buf[cur] (t-2) done
      const int kv0 = t * 64;

      bf16x8 kf[4][2];
#pragma unroll
      for (int n = 0; n < 4; ++n)
#pragma unroll
        for (int kc = 0; kc < 2; ++kc)
          kf[n][kc] = *(const bf16x8*)&Ksm[cur][n * 16 + l15][kc * 32 + l4 * 8];

      f32x4 sacc[4] = {};
#pragma unroll
      for (int n = 0; n < 4; ++n) {
        sacc[n] = mfma16(kf[n][0], qf[0], sacc[n]);
        sacc[n] = mfma16(kf[n][1], qf[1], sacc[n]);
      }

      bf16x8 vf[2][4];
#pragma unroll
      for (int kb = 0; kb < 2; ++kb)
#pragma unroll
        for (int n = 0; n < 4; ++n)
          vf[kb][n] = *(const bf16x8*)&Vsm[cur][n * 16 + l15][kb * 32 + l4 * 8];

      if (kv0 + 63 > q0) {
#pragma unroll
        for (int n = 0; n < 4; ++n)
#pragma unroll
          for (int i = 0; i < 4; ++i)
            if (kv0 + n * 16 + 4 * l4 + i > q0 + l15) sacc[n][i] = -1e30f;
      }

      {
        float a0 = fmaxf(fmaxf(sacc[0][0], sacc[0][1]),
                         fmaxf(sacc[0][2], sacc[0][3]));
        float a1 = fmaxf(fmaxf(sacc[1][0], sacc[1][1]),
                         fmaxf(sacc[1][2], sacc[1][3]));
        float a2 = fmaxf(fmaxf(sacc[2][0], sacc[2][1]),
                         fmaxf(sacc[2][2], sacc[2][3]));
        float a3 = fmaxf(fmaxf(sacc[3][0], sacc[3][1]),
                         fmaxf(sacc[3][2], sacc[3][3]));
        float tm = fmaxf(fmaxf(a0, a1), fmaxf(a2, a3));
        tm = redmax16(tm);
        tm = redmax32(tm);
        float mr = mrun;
        if (__all(tm <= mr + 8.0f)) {
          // defer-max: no rescale; P bounded by 2^8
          float rs = 0.f;
#pragma unroll
          for (int n = 0; n < 4; ++n)
#pragma unroll
            for (int i = 0; i < 4; ++i) {
              float pv = fexp2(sacc[n][i] - mr);
              sacc[n][i] = pv;
              rs += pv;
            }
          rs = redadd16(rs);
          rs = redadd32(rs);
          lrun += rs;
        } else {
          float mnew = fmaxf(mr, tm);
          float corr = fexp2(mr - mnew);
          mrun = mnew;
          float rs = 0.f;
#pragma unroll
          for (int n = 0; n < 4; ++n)
#pragma unroll
            for (int i = 0; i < 4; ++i) {
              float pv = fexp2(sacc[n][i] - mnew);
              sacc[n][i] = pv;
              rs += pv;
            }
          rs = redadd16(rs);
          rs = redadd32(rs);
          lrun = lrun * corr + rs;
          float cc0 = __shfl(corr, shbase + 0);
          float cc1 = __shfl(corr, shbase + 1);
          float cc2 = __shfl(corr, shbase + 2);
          float cc3 = __shfl(corr, shbase + 3);
#pragma unroll
          for (int n = 0; n < 4; ++n) {
            oacc[n][0] *= cc0; oacc[n][1] *= cc1;
            oacc[n][2] *= cc2; oacc[n][3] *= cc3;
          }
        }
#pragma unroll
        for (int n = 0; n < 4; ++n) {
          uint2 pkk;
          pkk.x = cvtpk(sacc[n][0], sacc[n][1]);
          pkk.y = cvtpk(sacc[n][2], sacc[n][3]);
          *(uint2*)&P[l15][n * 16 + 4 * l4] = pkk;
        }
      }

#pragma unroll
      for (int kb = 0; kb < 2; ++kb) {
        bf16x8 pf = *(const bf16x8*)&P[l15][kb * 32 + l4 * 8];
#pragma unroll
        for (int n = 0; n < 4; ++n)
          oacc[n] = mfma16(pf, vf[kb][n], oacc[n]);
      }

      if (t + 1 < nt) {  // stage tile t+1 into the other buffer (off critical path)
        *(uint4*)&Ksm[cur ^ 1][sr][scb]     = ka0;
        *(uint4*)&Ksm[cur ^ 1][sr][scb + 8] = ka1;
        *(uint4*)&Vsm[cur ^ 1][sr][scb]     = va0;
        *(uint4*)&Vsm[cur ^ 1][sr][scb + 8] = va1;
      }
    }

    // finalize this wave's 16 rows directly
    {
      float invm = 1.0f / lrun;
#pragma unroll
      for (int i = 0; i < 4; ++i) {
        float iv = __shfl(invm, shbase + i);
        int srow = q0 + 4 * l4 + i;
#pragma unroll
        for (int n = 0; n < 4; ++n) {
          int d = h * HSZ + n * 16 + l15;
          Ob[((size_t)b * S_LEN + srow) * DMODEL + d] = f2bf(oacc[n][i] * iv);
        }
      }
    }
  }
}

extern "C" void kernel_launch(void* const* d_in, const int* in_sizes, int n_in,
                              void* d_out, int out_size, void* d_ws, size_t ws_size,
                              hipStream_t stream) {
  const float* q  = (const float*)d_in[0];
  const float* Wq = (const float*)d_in[1];
  const float* bq = (const float*)d_in[2];
  const float* Wk = (const float*)d_in[3];
  const float* bk = (const float*)d_in[4];
  const float* Wv = (const float*)d_in[5];
  const float* bv = (const float*)d_in[6];
  const float* Wo = (const float*)d_in[7];
  const float* bo = (const float*)d_in[8];

  char* ws = (char*)d_ws;
  const size_t MB = 1024 * 1024;
  u16* Xb  = (u16*)(ws + 0);        // 8 MB  [4096][1024] bf16
  u16* WqT = (u16*)(ws + 8 * MB);   // 2 MB  [N][K] bf16
  u16* WkT = (u16*)(ws + 10 * MB);
  u16* WvT = (u16*)(ws + 12 * MB);
  u16* WoT = (u16*)(ws + 14 * MB);
  u16* Qh  = (u16*)(ws + 16 * MB);  // 8 MB  [bh][S][64]
  u16* Kh  = (u16*)(ws + 24 * MB);
  u16* Vh  = (u16*)(ws + 32 * MB);
  u16* Vt  = (u16*)(ws + 40 * MB);  // 8 MB  [bh][64][S]
  u16* Ob  = (u16*)(ws + 48 * MB);  // 8 MB  [B,S,D]

  prep_kernel<<<5120, 256, 0, stream>>>(q, Xb, Wq, Wk, Wv, Wo,
                                        WqT, WkT, WvT, WoT);
  gemm_qkv_kernel<<<768, 256, 0, stream>>>(Xb, WqT, WkT, WvT,
                                           bq, bk, bv, Qh, Kh, Vh);
  transpose_v_kernel<<<dim3(32, 32), 256, 0, stream>>>(Vh, Vt);
  attn_kernel<<<512, 256, 0, stream>>>(Qh, Kh, Vt, Ob);
  gemm_out_kernel<<<512, 256, 0, stream>>>(Ob, WoT, bo, (float*)d_out);
}